// Round 9
// baseline (6357.134 us; speedup 1.0000x reference)
//
#include <hip/hip_runtime.h>
#include <math.h>

#define T_LEN 1000
#define BATCH 16
#define MEL   80
#define HID   512
#define NCLS  64
#define SL    8        // column slices (blocks) per chain (8 x 512 threads)
#define CNT_STRIDE 32  // ints per chain counter line (128 B padding)

__device__ __forceinline__ float fast_tanh(float x) {
    float e = __expf(2.0f * x);
    return 1.0f - 2.0f / (e + 1.0f);
}
__device__ __forceinline__ float fast_sigmoid(float x) {
    return 1.0f / (1.0f + __expf(-x));
}

// ---- LLC (coherence-point) bulk-data ops: sc0 sc1 bypass L1+L2.
// PROVEN USE (r6): bulk data loads/stores gated by a __hip_atomic flag.
// NEVER use these for polling (r7/r8 lesson: livelock).
__device__ __forceinline__ void llc_load16(const float* base, float4 (&r)[16]) {
    asm volatile(
        "global_load_dwordx4 %0, %16, off sc0 sc1\n\t"
        "global_load_dwordx4 %1, %16, off offset:128 sc0 sc1\n\t"
        "global_load_dwordx4 %2, %16, off offset:256 sc0 sc1\n\t"
        "global_load_dwordx4 %3, %16, off offset:384 sc0 sc1\n\t"
        "global_load_dwordx4 %4, %16, off offset:512 sc0 sc1\n\t"
        "global_load_dwordx4 %5, %16, off offset:640 sc0 sc1\n\t"
        "global_load_dwordx4 %6, %16, off offset:768 sc0 sc1\n\t"
        "global_load_dwordx4 %7, %16, off offset:896 sc0 sc1\n\t"
        "global_load_dwordx4 %8, %16, off offset:1024 sc0 sc1\n\t"
        "global_load_dwordx4 %9, %16, off offset:1152 sc0 sc1\n\t"
        "global_load_dwordx4 %10, %16, off offset:1280 sc0 sc1\n\t"
        "global_load_dwordx4 %11, %16, off offset:1408 sc0 sc1\n\t"
        "global_load_dwordx4 %12, %16, off offset:1536 sc0 sc1\n\t"
        "global_load_dwordx4 %13, %16, off offset:1664 sc0 sc1\n\t"
        "global_load_dwordx4 %14, %16, off offset:1792 sc0 sc1\n\t"
        "global_load_dwordx4 %15, %16, off offset:1920 sc0 sc1\n\t"
        "s_waitcnt vmcnt(0)"
        : "=&v"(r[0]), "=&v"(r[1]), "=&v"(r[2]), "=&v"(r[3]),
          "=&v"(r[4]), "=&v"(r[5]), "=&v"(r[6]), "=&v"(r[7]),
          "=&v"(r[8]), "=&v"(r[9]), "=&v"(r[10]), "=&v"(r[11]),
          "=&v"(r[12]), "=&v"(r[13]), "=&v"(r[14]), "=&v"(r[15])
        : "v"(base)
        : "memory");
}
__device__ __forceinline__ void llc_store_f32(float* p, float v) {
    asm volatile("global_store_dword %0, %1, off sc0 sc1" :: "v"(p), "v"(v) : "memory");
}
__device__ __forceinline__ void vm_drain() {
    asm volatile("s_waitcnt vmcnt(0)" ::: "memory");
}

// K0: zero inter-block state
__global__ void k0_init(float* h_buf, int* cnt) {
    int i = blockIdx.x * 256 + threadIdx.x;
    if (i < BATCH * HID) h_buf[i] = 0.f;
    if (i < BATCH * CNT_STRIDE) cnt[i] = 0;
}

// K1: per t: x_norm0 from feats, be0 = x_norm0 @ B0^T
__global__ __launch_bounds__(256) void k1_be0(const float* __restrict__ feats,
                                              const float* __restrict__ B0,
                                              float* __restrict__ be0) {
    const int t = blockIdx.x;
    const int tid = threadIdx.x;
    __shared__ float xf[BATCH][MEL];
    __shared__ float sc[BATCH];
    for (int idx = tid; idx < BATCH * MEL; idx += 256) {
        int b = idx / MEL, m = idx % MEL;
        xf[b][m] = feats[b * (T_LEN * MEL) + t * MEL + m];
    }
    __syncthreads();
    if (tid < BATCH) {
        float ss = 0.f;
        for (int m = 0; m < MEL; ++m) { float v = xf[tid][m]; ss += v * v; }
        sc[tid] = fmaxf(sqrtf(ss), 1e-6f);
    }
    __syncthreads();
    for (int idx = tid; idx < BATCH * MEL; idx += 256) {
        int b = idx / MEL, m = idx % MEL;
        float v = xf[b][m] / sc[b];
        xf[b][m] = fminf(fmaxf(v, -1.f), 1.f);
    }
    __syncthreads();
    for (int j = tid; j < HID; j += 256) {
        float acc[BATCH];
        #pragma unroll
        for (int b = 0; b < BATCH; ++b) acc[b] = 0.f;
        const float* brow = B0 + j * MEL;
        for (int k = 0; k < MEL; k += 4) {
            float4 w = *(const float4*)(brow + k);
            #pragma unroll
            for (int b = 0; b < BATCH; ++b) {
                float4 xv = *(const float4*)(&xf[b][k]);
                acc[b] += w.x * xv.x + w.y * xv.y + w.z * xv.z + w.w * xv.w;
            }
        }
        #pragma unroll
        for (int b = 0; b < BATCH; ++b)
            be0[(t * BATCH + b) * HID + j] = acc[b];
    }
}

// K2: per t: x_norm1 from be0, be1 = x_norm1 @ B1^T, store xs1
__global__ __launch_bounds__(256) void k2_be1(const float* __restrict__ be0,
                                              const float* __restrict__ B1,
                                              float* __restrict__ be1,
                                              float* __restrict__ xs1) {
    const int t = blockIdx.x;
    const int tid = threadIdx.x;
    __shared__ float xn[BATCH][HID];
    __shared__ float sc[BATCH];
    __shared__ float psum[BATCH][16];
    for (int idx = tid; idx < BATCH * HID; idx += 256) {
        int b = idx >> 9, k = idx & 511;
        xn[b][k] = be0[(t * BATCH + b) * HID + k];
    }
    __syncthreads();
    {
        int b = tid >> 4, l = tid & 15;
        float ss = 0.f;
        for (int k = l; k < HID; k += 16) { float v = xn[b][k]; ss += v * v; }
        psum[b][l] = ss;
    }
    __syncthreads();
    if (tid < BATCH) {
        float ss = 0.f;
        #pragma unroll
        for (int l = 0; l < 16; ++l) ss += psum[tid][l];
        float s = fmaxf(sqrtf(ss), 1e-6f);
        sc[tid] = s;
        xs1[t * BATCH + tid] = s;
    }
    __syncthreads();
    for (int idx = tid; idx < BATCH * HID; idx += 256) {
        int b = idx >> 9, k = idx & 511;
        float v = xn[b][k] / sc[b];
        xn[b][k] = fminf(fmaxf(v, -1.f), 1.f);
    }
    __syncthreads();
    for (int j = tid; j < HID; j += 256) {
        float acc[BATCH];
        #pragma unroll
        for (int b = 0; b < BATCH; ++b) acc[b] = 0.f;
        const float* brow = B1 + j * HID;
        for (int k = 0; k < HID; k += 4) {
            float4 w = *(const float4*)(brow + k);
            #pragma unroll
            for (int b = 0; b < BATCH; ++b) {
                float4 xv = *(const float4*)(&xn[b][k]);
                acc[b] += w.x * xv.x + w.y * xv.y + w.z * xv.z + w.w * xv.w;
            }
        }
        #pragma unroll
        for (int b = 0; b < BATCH; ++b)
            be1[(t * BATCH + b) * HID + j] = acc[b];
    }
}

// K3: sequential recurrence. 8 blocks/chain x 8 waves (512 thr); each wave
// owns 8 columns; weights asm-loaded (non-rematerializable => resident);
// single monotonic per-chain counter barrier (8 RMWs/phase, single-address
// __hip_atomic_load poll — the r6-proven protocol).
__global__ __launch_bounds__(512, 1) void k3_wave(
    const float* __restrict__ be0, const float* __restrict__ be1,
    const float* __restrict__ xs1,
    const float* __restrict__ C1, const float* __restrict__ W1,
    const float* __restrict__ a1, const float* __restrict__ tau,
    const float* __restrict__ gam,
    float* __restrict__ h1s,
    float* h_buf, float* err_buf, int* cnt_arr)
{
    const int chain = blockIdx.x & 15;
    const int slice = blockIdx.x >> 4;        // 0..7
    const int tid = threadIdx.x;
    const int w = tid >> 6;                   // wave in block 0..7
    const int lane = tid & 63;
    const int ks = lane & 7;                  // k-group within column
    const int colw = lane >> 3;               // column within wave 0..7
    const int j = slice * 64 + w * 8 + colw;  // output column 0..511
    const bool lead = (ks == 0);

    // 32 float4 = 128 regs of weights, asm-defined (cannot be rematerialized)
    float4 wC[16], wW[16];
    llc_load16(C1 + (size_t)j * HID + ks * 4, wC);
    llc_load16(W1 + (size_t)j * HID + ks * 4, wW);

    const float tauv = tau[0], gamv = gam[0];
    const float siga = fast_sigmoid(a1[j]);

    float* hb = h_buf + chain * HID;
    float* eb = err_buf + chain * HID;
    int* cnt = cnt_arr + chain * CNT_STRIDE;
    const float* hbase = hb + ks * 4;
    const float* ebase = eb + ks * 4;

    float hj = 0.f;
    float cur_be0 = 0.f, cur_be1 = 0.f;
    if (lead) {
        cur_be0 = __builtin_nontemporal_load(&be0[(size_t)chain * HID + j]);
        cur_be1 = __builtin_nontemporal_load(&be1[(size_t)chain * HID + j]);
    }
    float cur_xs = __builtin_nontemporal_load(&xs1[chain]);

    for (int t = 0; t < T_LEN; ++t) {
        // prefetch next step's streams (overlaps the polls below)
        float nxt_be0 = 0.f, nxt_be1 = 0.f, nxt_xs = 0.f;
        if (t + 1 < T_LEN) {
            const size_t nrow = (size_t)((t + 1) * BATCH + chain) * HID;
            if (lead) {
                nxt_be0 = __builtin_nontemporal_load(&be0[nrow + j]);
                nxt_be1 = __builtin_nontemporal_load(&be1[nrow + j]);
            }
            nxt_xs = __builtin_nontemporal_load(&xs1[(t + 1) * BATCH + chain]);
        }

        // ---- wait: h(t) ready  (cnt >= 2*SL*t) ----
        {
            const int tok = 2 * SL * t;
            while (__hip_atomic_load(cnt, __ATOMIC_RELAXED,
                                     __HIP_MEMORY_SCOPE_AGENT) < tok)
                __builtin_amdgcn_s_sleep(1);
        }

        // ---- phase 1: dp = (h @ C1^T)[j], publish err ----
        float4 hv[16];
        llc_load16(hbase, hv);
        float dp = 0.f;
        #pragma unroll
        for (int i = 0; i < 16; ++i)
            dp += wC[i].x * hv[i].x + wC[i].y * hv[i].y
                + wC[i].z * hv[i].z + wC[i].w * hv[i].w;
        dp += __shfl_down(dp, 4, 8);
        dp += __shfl_down(dp, 2, 8);
        dp += __shfl_down(dp, 1, 8);
        if (lead) {
            float e = cur_be0 - fast_tanh(dp) * cur_xs;
            llc_store_f32(&eb[j], e);
        }
        vm_drain();                      // err stores at coherence point
        __syncthreads();                 // all 8 waves of block drained
        if (tid == 0) atomicAdd(cnt, 1); // fire-and-forget arrival

        // ---- wait: err(t) ready  (cnt >= 2*SL*t + SL) ----
        {
            const int tok = 2 * SL * t + SL;
            while (__hip_atomic_load(cnt, __ATOMIC_RELAXED,
                                     __HIP_MEMORY_SCOPE_AGENT) < tok)
                __builtin_amdgcn_s_sleep(1);
        }

        // ---- phase 2: ssq from loaded err (8x dup => /8), ee = err@W1^T ----
        float4 ev[16];
        llc_load16(ebase, ev);
        float ee = 0.f, sq = 0.f;
        #pragma unroll
        for (int i = 0; i < 16; ++i) {
            ee += wW[i].x * ev[i].x + wW[i].y * ev[i].y
                + wW[i].z * ev[i].z + wW[i].w * ev[i].w;
            sq += ev[i].x * ev[i].x + ev[i].y * ev[i].y
                + ev[i].z * ev[i].z + ev[i].w * ev[i].w;
        }
        #pragma unroll
        for (int off = 32; off > 0; off >>= 1) sq += __shfl_down(sq, off, 64);
        float ssT = __shfl(sq, 0, 64) * 0.125f;
        ee += __shfl_down(ee, 4, 8);
        ee += __shfl_down(ee, 2, 8);
        ee += __shfl_down(ee, 1, 8);
        if (lead) {
            float rel = fminf(sqrtf(ssT) / cur_xs, 4.0f);
            float s = fast_sigmoid((rel - tauv) / gamv);
            float input_h = hj * 0.2f + cur_be1 * 0.6f + ee * s * 0.2f;
            float g = s * siga;
            hj = hj * (1.f - g) + fast_tanh(input_h) * g;
            llc_store_f32(&hb[j], hj);
        }
        vm_drain();                      // h stores at coherence point
        __syncthreads();
        if (tid == 0) atomicAdd(cnt, 1);
        // h1s output store off the critical path (completes during next poll)
        if (lead)
            __builtin_nontemporal_store(hj, &h1s[(size_t)(t * BATCH + chain) * HID + j]);

        cur_be0 = nxt_be0; cur_be1 = nxt_be1; cur_xs = nxt_xs;
    }
}

// K4: head matmul out[b,t,c] = [h1 || be1] @ head_w^T + head_b
__global__ __launch_bounds__(1024) void k4_head(const float* __restrict__ h1s,
                                                const float* __restrict__ be1,
                                                const float* __restrict__ head_w,
                                                const float* __restrict__ head_b,
                                                float* __restrict__ out) {
    const int t = blockIdx.x;
    const int tid = threadIdx.x;
    const int c = tid >> 4;
    const int b = tid & 15;
    const float* hw = head_w + c * (2 * HID);
    const float* x1 = h1s + (size_t)(t * BATCH + b) * HID;
    const float* x2 = be1 + (size_t)(t * BATCH + b) * HID;
    float acc0 = head_b[c], acc1 = 0.f;
    for (int k = 0; k < HID; k += 4) {
        float4 w = *(const float4*)(hw + k);
        float4 xv = *(const float4*)(x1 + k);
        acc0 += w.x * xv.x + w.y * xv.y + w.z * xv.z + w.w * xv.w;
    }
    for (int k = 0; k < HID; k += 4) {
        float4 w = *(const float4*)(hw + HID + k);
        float4 xv = *(const float4*)(x2 + k);
        acc1 += w.x * xv.x + w.y * xv.y + w.z * xv.z + w.w * xv.w;
    }
    out[b * (T_LEN * NCLS) + t * NCLS + c] = acc0 + acc1;
}

extern "C" void kernel_launch(void* const* d_in, const int* in_sizes, int n_in,
                              void* d_out, int out_size, void* d_ws, size_t ws_size,
                              hipStream_t stream) {
    const float* feats  = (const float*)d_in[0];
    const float* B0     = (const float*)d_in[2];
    const float* C1     = (const float*)d_in[7];
    const float* B1     = (const float*)d_in[8];
    const float* W1     = (const float*)d_in[9];
    const float* a1     = (const float*)d_in[10];
    const float* tau1   = (const float*)d_in[11];
    const float* gam1   = (const float*)d_in[12];
    const float* head_w = (const float*)d_in[13];
    const float* head_b = (const float*)d_in[14];
    float* out = (float*)d_out;

    float* be0   = (float*)d_ws;                          // T*B*HID
    float* be1   = be0 + (size_t)T_LEN * BATCH * HID;     // T*B*HID
    float* xs1   = be1 + (size_t)T_LEN * BATCH * HID;     // T*B
    float* h1s   = xs1 + (size_t)T_LEN * BATCH;           // T*B*HID
    float* h_buf = h1s + (size_t)T_LEN * BATCH * HID;     // B*HID
    float* ebuf  = h_buf + (size_t)BATCH * HID;           // B*HID
    int*   cnt   = (int*)(ebuf + (size_t)BATCH * HID);    // B*32

    hipLaunchKernelGGL(k0_init, dim3(32), dim3(256), 0, stream, h_buf, cnt);
    hipLaunchKernelGGL(k1_be0, dim3(T_LEN), dim3(256), 0, stream, feats, B0, be0);
    hipLaunchKernelGGL(k2_be1, dim3(T_LEN), dim3(256), 0, stream, be0, B1, be1, xs1);
    hipLaunchKernelGGL(k3_wave, dim3(BATCH * SL), dim3(512), 0, stream,
                       be0, be1, xs1, C1, W1, a1, tau1, gam1, h1s,
                       h_buf, ebuf, cnt);
    hipLaunchKernelGGL(k4_head, dim3(T_LEN), dim3(1024), 0, stream,
                       h1s, be1, head_w, head_b, out);
}